// Round 3
// baseline (108.316 us; speedup 1.0000x reference)
//
#include <hip/hip_runtime.h>
#include <cstdint>

typedef float v2f __attribute__((ext_vector_type(2)));
typedef float v4f __attribute__((ext_vector_type(4)));

#define N_PRED 8192
#define N_GT   32768
#define NN_BLK 256
#define PP     4
#define PRED_CHUNK (PP * NN_BLK)       // 1024
#define GT_TILE 512
#define N_GTC  (N_GT / GT_TILE)        // 64
#define ST     256
#define N_SC   (N_PRED / ST)           // 32
#define RCOFF  64.0f                   // keeps rep h > 0 for u32 atomicMax

// ws layout (primary): [0, 2MB) float nnchunk[64][8192]; then u32 repmax[8192]; then partials[32][3]
#define NNCHUNK_BYTES (N_GTC * N_PRED * 4)
#define WS_NEEDED     (NNCHUNK_BYTES + N_PRED * 4 + 32 * 3 * 4)

__device__ __forceinline__ v2f pk_fma(v2f a, v2f b, v2f c) {
    v2f d;
    asm("v_pk_fma_f32 %0, %1, %2, %3" : "=v"(d) : "v"(a), "v"(b), "v"(c));
    return d;
}
__device__ __forceinline__ float max3f(float a, float b, float c) {
    float d;
    asm("v_max3_f32 %0, %1, %2, %3" : "=v"(d) : "v"(a), "v"(b), "v"(c));
    return d;
}

__global__ __launch_bounds__(256) void init_kernel(unsigned int* repmax) {
    const int i = blockIdx.x * blockDim.x + threadIdx.x;
    if (i < N_PRED) repmax[i] = 0u;
}

// ---- NN bulk pass: per (pred-chunk, gt-chunk) block, exact max of
//      h = p.g - 0.5|g|^2 over the 512-gt tile. Value only, no atomics. ----
__global__ __launch_bounds__(256) void nn_kernel(const float* __restrict__ pred,
                                                 const float* __restrict__ gt,
                                                 float* __restrict__ nnchunk) {
    __shared__ alignas(16) float sx[GT_TILE], sy[GT_TILE], sz[GT_TILE], sw[GT_TILE];
    const int pc = blockIdx.x / N_GTC;
    const int gc = blockIdx.x % N_GTC;
    const int gbase = gc * GT_TILE;

    for (int k = threadIdx.x; k < GT_TILE; k += NN_BLK) {
        const int g = gbase + k;
        const float x = gt[g * 6 + 0], y = gt[g * 6 + 1], z = gt[g * 6 + 2];
        sx[k] = x; sy[k] = y; sz[k] = z;
        sw[k] = -0.5f * (x * x + y * y + z * z);
    }
    __syncthreads();

    v2f PX[PP], PY[PP], PZ[PP];
    float best[PP];
    const int pbase = pc * PRED_CHUNK + threadIdx.x;
#pragma unroll
    for (int q = 0; q < PP; ++q) {
        const int p = pbase + q * NN_BLK;
        const float x = pred[p * 6 + 0], y = pred[p * 6 + 1], z = pred[p * 6 + 2];
        v2f vx = {x, x}; v2f vy = {y, y}; v2f vz = {z, z};
        PX[q] = vx; PY[q] = vy; PZ[q] = vz;
        best[q] = -3.0e38f;
    }

#pragma unroll 2
    for (int k = 0; k < GT_TILE; k += 4) {
        const v4f gx4 = *(const v4f*)&sx[k];
        const v4f gy4 = *(const v4f*)&sy[k];
        const v4f gz4 = *(const v4f*)&sz[k];
        const v4f gw4 = *(const v4f*)&sw[k];
        const v2f gx01 = __builtin_shufflevector(gx4, gx4, 0, 1);
        const v2f gx23 = __builtin_shufflevector(gx4, gx4, 2, 3);
        const v2f gy01 = __builtin_shufflevector(gy4, gy4, 0, 1);
        const v2f gy23 = __builtin_shufflevector(gy4, gy4, 2, 3);
        const v2f gz01 = __builtin_shufflevector(gz4, gz4, 0, 1);
        const v2f gz23 = __builtin_shufflevector(gz4, gz4, 2, 3);
        const v2f gw01 = __builtin_shufflevector(gw4, gw4, 0, 1);
        const v2f gw23 = __builtin_shufflevector(gw4, gw4, 2, 3);
#pragma unroll
        for (int q = 0; q < PP; ++q) {
            v2f h0 = pk_fma(PZ[q], gz01, gw01);
            h0 = pk_fma(PY[q], gy01, h0);
            h0 = pk_fma(PX[q], gx01, h0);
            v2f h1 = pk_fma(PZ[q], gz23, gw23);
            h1 = pk_fma(PY[q], gy23, h1);
            h1 = pk_fma(PX[q], gx23, h1);
            best[q] = max3f(best[q], h0.x, h0.y);
            best[q] = max3f(best[q], h1.x, h1.y);
        }
    }

#pragma unroll
    for (int q = 0; q < PP; ++q)
        nnchunk[gc * N_PRED + pbase + q * NN_BLK] = best[q];
}

// ---- Repulsion: exact max over j!=i of h = 64 + pi.pj - 0.5|pj|^2 ----
__global__ __launch_bounds__(256) void rep_kernel(const float* __restrict__ pred,
                                                  unsigned int* __restrict__ repmax) {
    __shared__ alignas(16) float sx[ST], sy[ST], sz[ST], sw[ST];
    const int pc = blockIdx.x / N_SC;
    const int sc = blockIdx.x % N_SC;
    const int sbase = sc * ST;
    const int pcbase = pc * PRED_CHUNK;

    {
        const int k = threadIdx.x;           // ST == NN_BLK
        const int g = sbase + k;
        const float x = pred[g * 6 + 0], y = pred[g * 6 + 1], z = pred[g * 6 + 2];
        sx[k] = x; sy[k] = y; sz[k] = z;
        sw[k] = RCOFF - 0.5f * (x * x + y * y + z * z);
    }
    __syncthreads();

    float pxs[PP], pys[PP], pzs[PP], best[PP];
    const int pbase = pcbase + threadIdx.x;
#pragma unroll
    for (int q = 0; q < PP; ++q) {
        const int p = pbase + q * NN_BLK;
        pxs[q] = pred[p * 6 + 0];
        pys[q] = pred[p * 6 + 1];
        pzs[q] = pred[p * 6 + 2];
        best[q] = -3.0e38f;
    }

    const bool excl = (sbase >= pcbase) && (sbase < pcbase + PRED_CHUNK);
    if (excl) {
#pragma unroll 4
        for (int k = 0; k < ST; ++k) {
            const float gx = sx[k], gy = sy[k], gz = sz[k], gw = sw[k];
            const int j = sbase + k;
#pragma unroll
            for (int q = 0; q < PP; ++q) {
                float t = fmaf(pxs[q], gx, fmaf(pys[q], gy, fmaf(pzs[q], gz, gw)));
                t = (j == pbase + q * NN_BLK) ? -3.0e38f : t;
                best[q] = fmaxf(best[q], t);
            }
        }
    } else {
        v2f PX[PP], PY[PP], PZ[PP];
#pragma unroll
        for (int q = 0; q < PP; ++q) {
            v2f vx = {pxs[q], pxs[q]}; v2f vy = {pys[q], pys[q]}; v2f vz = {pzs[q], pzs[q]};
            PX[q] = vx; PY[q] = vy; PZ[q] = vz;
        }
#pragma unroll 2
        for (int k = 0; k < ST; k += 4) {
            const v4f gx4 = *(const v4f*)&sx[k];
            const v4f gy4 = *(const v4f*)&sy[k];
            const v4f gz4 = *(const v4f*)&sz[k];
            const v4f gw4 = *(const v4f*)&sw[k];
            const v2f gx01 = __builtin_shufflevector(gx4, gx4, 0, 1);
            const v2f gx23 = __builtin_shufflevector(gx4, gx4, 2, 3);
            const v2f gy01 = __builtin_shufflevector(gy4, gy4, 0, 1);
            const v2f gy23 = __builtin_shufflevector(gy4, gy4, 2, 3);
            const v2f gz01 = __builtin_shufflevector(gz4, gz4, 0, 1);
            const v2f gz23 = __builtin_shufflevector(gz4, gz4, 2, 3);
            const v2f gw01 = __builtin_shufflevector(gw4, gw4, 0, 1);
            const v2f gw23 = __builtin_shufflevector(gw4, gw4, 2, 3);
#pragma unroll
            for (int q = 0; q < PP; ++q) {
                v2f h0 = pk_fma(PZ[q], gz01, gw01);
                h0 = pk_fma(PY[q], gy01, h0);
                h0 = pk_fma(PX[q], gx01, h0);
                v2f h1 = pk_fma(PZ[q], gz23, gw23);
                h1 = pk_fma(PY[q], gy23, h1);
                h1 = pk_fma(PX[q], gx23, h1);
                best[q] = max3f(best[q], h0.x, h0.y);
                best[q] = max3f(best[q], h1.x, h1.y);
            }
        }
    }

#pragma unroll
    for (int q = 0; q < PP; ++q)
        atomicMax(&repmax[pbase + q * NN_BLK], __float_as_uint(best[q]));
}

// ---- Recovery + finalize: pick argmax chunk, exact rescan (numpy tie
//      semantics: first strict max = smallest index), then losses. ----
__device__ __forceinline__ float wave_reduce(float v) {
#pragma unroll
    for (int off = 32; off > 0; off >>= 1) v += __shfl_down(v, off, 64);
    return v;
}

template <bool USE_CHUNK>
__global__ __launch_bounds__(256) void finalize_kernel(const float* __restrict__ pred,
                                                       const float* __restrict__ gt,
                                                       const float* __restrict__ nnchunk,
                                                       const unsigned int* __restrict__ repmax,
                                                       float* __restrict__ partials) {
    const int p = blockIdx.x * blockDim.x + threadIdx.x;
    const float px = pred[p * 6 + 0], py = pred[p * 6 + 1], pz = pred[p * 6 + 2];

    int j = 0;
    if (USE_CHUNK) {
        float bm = -3.0e38f;
        int bgc = 0;
        for (int gc = 0; gc < N_GTC; ++gc) {
            const float m = nnchunk[gc * N_PRED + p];
            if (m > bm) { bm = m; bgc = gc; }
        }
        float bh = -3.0e38f;
        const int gb = bgc * GT_TILE;
#pragma unroll 4
        for (int k = 0; k < GT_TILE; ++k) {
            const int g = gb + k;
            const float x = gt[g * 6 + 0], y = gt[g * 6 + 1], z = gt[g * 6 + 2];
            const float w = -0.5f * (x * x + y * y + z * z);
            const float h = fmaf(px, x, fmaf(py, y, fmaf(pz, z, w)));
            if (h > bh) { bh = h; j = g; }
        }
    } else {
        float bh = -3.0e38f;
#pragma unroll 4
        for (int g = 0; g < N_GT; ++g) {
            const float x = gt[g * 6 + 0], y = gt[g * 6 + 1], z = gt[g * 6 + 2];
            const float w = -0.5f * (x * x + y * y + z * z);
            const float h = fmaf(px, x, fmaf(py, y, fmaf(pz, z, w)));
            if (h > bh) { bh = h; j = g; }
        }
    }

    const float gx = gt[j * 6 + 0], gy = gt[j * 6 + 1], gz = gt[j * 6 + 2];
    const float dx = px - gx, dy = py - gy, dz = pz - gz;
    float att = dx * dx + dy * dy + dz * dz;

    const float pnx = pred[p * 6 + 3], pny = pred[p * 6 + 4], pnz = pred[p * 6 + 5];
    const float gnx = gt[j * 6 + 3],   gny = gt[j * 6 + 4],   gnz = gt[j * 6 + 5];
    const float pl = fmaxf(sqrtf(pnx * pnx + pny * pny + pnz * pnz), 1e-5f);
    const float gl = fmaxf(sqrtf(gnx * gnx + gny * gny + gnz * gnz), 1e-5f);
    float nrm = 1.0f - (pnx * gnx + pny * gny + pnz * gnz) / (pl * gl);

    // d^2 = |p|^2 + 2*RCOFF - 2*h_max
    const float h = __uint_as_float(repmax[p]);
    float d2 = fmaf(-2.0f, h, px * px + py * py + pz * pz + 2.0f * RCOFF);
    d2 = fmaxf(d2, 0.0f);
    const float xarg = 100.0f * (0.3f - sqrtf(d2));
    const float sp = fmaxf(xarg, 0.0f) + log1pf(expf(-fabsf(xarg)));
    float rep = sp * sp;

    att = wave_reduce(att);
    nrm = wave_reduce(nrm);
    rep = wave_reduce(rep);

    __shared__ float red[3][4];
    const int wave = threadIdx.x >> 6;
    const int lane = threadIdx.x & 63;
    if (lane == 0) {
        red[0][wave] = att;
        red[1][wave] = nrm;
        red[2][wave] = rep;
    }
    __syncthreads();
    if (threadIdx.x == 0) {
        partials[blockIdx.x * 3 + 0] = red[0][0] + red[0][1] + red[0][2] + red[0][3];
        partials[blockIdx.x * 3 + 1] = red[1][0] + red[1][1] + red[1][2] + red[1][3];
        partials[blockIdx.x * 3 + 2] = red[2][0] + red[2][1] + red[2][2] + red[2][3];
    }
}

__global__ void combine_kernel(const float* __restrict__ partials, float* __restrict__ out) {
    if (threadIdx.x == 0 && blockIdx.x == 0) {
        float a = 0.f, n = 0.f, r = 0.f;
        for (int b = 0; b < 32; ++b) {
            a += partials[b * 3 + 0];
            n += partials[b * 3 + 1];
            r += partials[b * 3 + 2];
        }
        out[0] = a / (float)(N_PRED * 3) + r / (float)N_PRED + 10.0f * (n / (float)N_PRED);
    }
}

extern "C" void kernel_launch(void* const* d_in, const int* in_sizes, int n_in,
                              void* d_out, int out_size, void* d_ws, size_t ws_size,
                              hipStream_t stream) {
    const float* pred = (const float*)d_in[0];   // (8192, 6)
    const float* gt   = (const float*)d_in[3];   // (32768, 6)
    float* out = (float*)d_out;
    char* ws = (char*)d_ws;

    const bool use_chunk = ws_size >= (size_t)WS_NEEDED;
    float* nnchunk;
    unsigned int* repmax;
    float* partials;
    if (use_chunk) {
        nnchunk  = (float*)ws;
        repmax   = (unsigned int*)(ws + NNCHUNK_BYTES);
        partials = (float*)(ws + NNCHUNK_BYTES + N_PRED * 4);
    } else {
        nnchunk  = nullptr;
        repmax   = (unsigned int*)ws;
        partials = (float*)(ws + N_PRED * 4);
    }

    init_kernel<<<N_PRED / 256, 256, 0, stream>>>(repmax);
    if (use_chunk)
        nn_kernel<<<(N_PRED / PRED_CHUNK) * N_GTC, NN_BLK, 0, stream>>>(pred, gt, nnchunk);
    rep_kernel<<<(N_PRED / PRED_CHUNK) * N_SC, NN_BLK, 0, stream>>>(pred, repmax);
    if (use_chunk)
        finalize_kernel<true><<<N_PRED / 256, 256, 0, stream>>>(pred, gt, nnchunk, repmax, partials);
    else
        finalize_kernel<false><<<N_PRED / 256, 256, 0, stream>>>(pred, gt, nnchunk, repmax, partials);
    combine_kernel<<<1, 64, 0, stream>>>(partials, out);
}

// Round 4
// 51.922 us; speedup vs baseline: 2.0861x; 2.0861x over previous
//
#include <hip/hip_runtime.h>
#include <cstdint>

typedef float v2f __attribute__((ext_vector_type(2)));
typedef float v4f __attribute__((ext_vector_type(4)));

#define N_PRED 8192
#define N_GT   32768

// pair_kernel geometry
#define BLK      256
#define NN_PCH   512                    // preds per nn block (PP=2)
#define NN_TILE  1024                   // gt per nn block tile
#define NN_NPC   (N_PRED / NN_PCH)      // 16 pred chunks
#define NN_NGC   (N_GT / NN_TILE)       // 32 gt chunks
#define NN_BLOCKS (NN_NPC * NN_NGC)     // 512
#define RP_PCH   512                    // preds per rep block (PP=2)
#define RP_TILE  512                    // self tile
#define RP_NPC   (N_PRED / RP_PCH)      // 16
#define RP_NSC   (N_PRED / RP_TILE)     // 16
#define RP_BLOCKS (RP_NPC * RP_NSC)     // 256

// ws layout: float nnchunk[8192][32] (1MB) | float repchunk[8192][16] (512KB)
//            | float partials[2048][3] (24KB)   -- total 1.56MB (proven fits)
#define OFF_REP  (N_PRED * NN_NGC * 4)
#define OFF_PART (OFF_REP + N_PRED * RP_NSC * 4)

__device__ __forceinline__ v2f pk_fma(v2f a, v2f b, v2f c) {
    v2f d;
    asm("v_pk_fma_f32 %0, %1, %2, %3" : "=v"(d) : "v"(a), "v"(b), "v"(c));
    return d;
}
__device__ __forceinline__ float max3f(float a, float b, float c) {
    float d;
    asm("v_max3_f32 %0, %1, %2, %3" : "=v"(d) : "v"(a), "v"(b), "v"(c));
    return d;
}

// ---- fused NN + repulsion bulk pass: exact per-(pred, chunk) max of
//      h = p.q - 0.5|q|^2. Value-only, no atomics, no init. ----
__global__ __launch_bounds__(256) void pair_kernel(const float* __restrict__ pred,
                                                   const float* __restrict__ gt,
                                                   float* __restrict__ nnchunk,
                                                   float* __restrict__ repchunk) {
    __shared__ alignas(16) float sx[NN_TILE], sy[NN_TILE], sz[NN_TILE], sw[NN_TILE];

    if (blockIdx.x < NN_BLOCKS) {
        // ---------- NN part: pred vs gt ----------
        const int pc = blockIdx.x >> 5;            // / NN_NGC
        const int gc = blockIdx.x & (NN_NGC - 1);
        const int gbase = gc * NN_TILE;

        for (int k = threadIdx.x; k < NN_TILE; k += BLK) {
            const int g = gbase + k;
            const float x = gt[g * 6 + 0], y = gt[g * 6 + 1], z = gt[g * 6 + 2];
            sx[k] = x; sy[k] = y; sz[k] = z;
            sw[k] = -0.5f * (x * x + y * y + z * z);
        }
        __syncthreads();

        const int pbase = pc * NN_PCH + threadIdx.x;
        v2f PX[2], PY[2], PZ[2];
        float bA[2], bB[2];
#pragma unroll
        for (int q = 0; q < 2; ++q) {
            const int p = pbase + q * BLK;
            const float x = pred[p * 6 + 0], y = pred[p * 6 + 1], z = pred[p * 6 + 2];
            v2f vx = {x, x}; v2f vy = {y, y}; v2f vz = {z, z};
            PX[q] = vx; PY[q] = vy; PZ[q] = vz;
            bA[q] = -3.0e38f; bB[q] = -3.0e38f;
        }

#pragma unroll 2
        for (int k = 0; k < NN_TILE; k += 4) {
            const v4f gx4 = *(const v4f*)&sx[k];
            const v4f gy4 = *(const v4f*)&sy[k];
            const v4f gz4 = *(const v4f*)&sz[k];
            const v4f gw4 = *(const v4f*)&sw[k];
            const v2f gx01 = __builtin_shufflevector(gx4, gx4, 0, 1);
            const v2f gx23 = __builtin_shufflevector(gx4, gx4, 2, 3);
            const v2f gy01 = __builtin_shufflevector(gy4, gy4, 0, 1);
            const v2f gy23 = __builtin_shufflevector(gy4, gy4, 2, 3);
            const v2f gz01 = __builtin_shufflevector(gz4, gz4, 0, 1);
            const v2f gz23 = __builtin_shufflevector(gz4, gz4, 2, 3);
            const v2f gw01 = __builtin_shufflevector(gw4, gw4, 0, 1);
            const v2f gw23 = __builtin_shufflevector(gw4, gw4, 2, 3);
#pragma unroll
            for (int q = 0; q < 2; ++q) {
                v2f h0 = pk_fma(PZ[q], gz01, gw01);
                h0 = pk_fma(PY[q], gy01, h0);
                h0 = pk_fma(PX[q], gx01, h0);
                v2f h1 = pk_fma(PZ[q], gz23, gw23);
                h1 = pk_fma(PY[q], gy23, h1);
                h1 = pk_fma(PX[q], gx23, h1);
                bA[q] = max3f(bA[q], h0.x, h0.y);
                bB[q] = max3f(bB[q], h1.x, h1.y);
            }
        }

#pragma unroll
        for (int q = 0; q < 2; ++q)
            nnchunk[(pbase + q * BLK) * NN_NGC + gc] = fmaxf(bA[q], bB[q]);

    } else {
        // ---------- Repulsion part: pred vs pred, exclude self ----------
        const int rb = blockIdx.x - NN_BLOCKS;
        const int pc = rb >> 4;                  // / RP_NSC
        const int sc = rb & (RP_NSC - 1);
        const int sbase = sc * RP_TILE;
        const int pcbase = pc * RP_PCH;

        for (int k = threadIdx.x; k < RP_TILE; k += BLK) {
            const int g = sbase + k;
            const float x = pred[g * 6 + 0], y = pred[g * 6 + 1], z = pred[g * 6 + 2];
            sx[k] = x; sy[k] = y; sz[k] = z;
            sw[k] = -0.5f * (x * x + y * y + z * z);
        }
        __syncthreads();

        const int pbase = pcbase + threadIdx.x;
        float best[2];
        float pxs[2], pys[2], pzs[2];
#pragma unroll
        for (int q = 0; q < 2; ++q) {
            const int p = pbase + q * BLK;
            pxs[q] = pred[p * 6 + 0];
            pys[q] = pred[p * 6 + 1];
            pzs[q] = pred[p * 6 + 2];
            best[q] = -3.0e38f;
        }

        if (pc == sc) {
            // diagonal block: scalar loop with self exclusion
#pragma unroll 4
            for (int k = 0; k < RP_TILE; ++k) {
                const float gx = sx[k], gy = sy[k], gz = sz[k], gw = sw[k];
#pragma unroll
                for (int q = 0; q < 2; ++q) {
                    float t = fmaf(pxs[q], gx, fmaf(pys[q], gy, fmaf(pzs[q], gz, gw)));
                    t = (k == q * BLK + (int)threadIdx.x) ? -3.0e38f : t;
                    best[q] = fmaxf(best[q], t);
                }
            }
        } else {
            v2f PX[2], PY[2], PZ[2];
            float bB[2] = {-3.0e38f, -3.0e38f};
#pragma unroll
            for (int q = 0; q < 2; ++q) {
                v2f vx = {pxs[q], pxs[q]}; v2f vy = {pys[q], pys[q]}; v2f vz = {pzs[q], pzs[q]};
                PX[q] = vx; PY[q] = vy; PZ[q] = vz;
            }
#pragma unroll 2
            for (int k = 0; k < RP_TILE; k += 4) {
                const v4f gx4 = *(const v4f*)&sx[k];
                const v4f gy4 = *(const v4f*)&sy[k];
                const v4f gz4 = *(const v4f*)&sz[k];
                const v4f gw4 = *(const v4f*)&sw[k];
                const v2f gx01 = __builtin_shufflevector(gx4, gx4, 0, 1);
                const v2f gx23 = __builtin_shufflevector(gx4, gx4, 2, 3);
                const v2f gy01 = __builtin_shufflevector(gy4, gy4, 0, 1);
                const v2f gy23 = __builtin_shufflevector(gy4, gy4, 2, 3);
                const v2f gz01 = __builtin_shufflevector(gz4, gz4, 0, 1);
                const v2f gz23 = __builtin_shufflevector(gz4, gz4, 2, 3);
                const v2f gw01 = __builtin_shufflevector(gw4, gw4, 0, 1);
                const v2f gw23 = __builtin_shufflevector(gw4, gw4, 2, 3);
#pragma unroll
                for (int q = 0; q < 2; ++q) {
                    v2f h0 = pk_fma(PZ[q], gz01, gw01);
                    h0 = pk_fma(PY[q], gy01, h0);
                    h0 = pk_fma(PX[q], gx01, h0);
                    v2f h1 = pk_fma(PZ[q], gz23, gw23);
                    h1 = pk_fma(PY[q], gy23, h1);
                    h1 = pk_fma(PX[q], gx23, h1);
                    best[q] = max3f(best[q], h0.x, h0.y);
                    bB[q] = max3f(bB[q], h1.x, h1.y);
                }
            }
            best[0] = fmaxf(best[0], bB[0]);
            best[1] = fmaxf(best[1], bB[1]);
        }

#pragma unroll
        for (int q = 0; q < 2; ++q)
            repchunk[(pbase + q * BLK) * RP_NSC + sc] = best[q];
    }
}

// ---- wave-per-pred recovery + losses + block partials ----
__global__ __launch_bounds__(256) void finalize_kernel(const float* __restrict__ pred,
                                                       const float* __restrict__ gt,
                                                       const float* __restrict__ nnchunk,
                                                       const float* __restrict__ repchunk,
                                                       float* __restrict__ partials) {
    const int wave = threadIdx.x >> 6;
    const int lane = threadIdx.x & 63;
    const int p = blockIdx.x * 4 + wave;

    // wave-uniform pred coords (broadcast loads)
    const float px = pred[p * 6 + 0], py = pred[p * 6 + 1], pz = pred[p * 6 + 2];

    // 1) argmax chunk (tie -> smaller chunk index)
    float m = -3.0e38f;
    int gci = 0;
    if (lane < NN_NGC) { m = nnchunk[p * NN_NGC + lane]; gci = lane; }
#pragma unroll
    for (int off = 32; off > 0; off >>= 1) {
        const float om = __shfl_xor(m, off);
        const int   oc = __shfl_xor(gci, off);
        const bool take = (om > m) || (om == m && oc < gci);
        m = take ? om : m;
        gci = take ? oc : gci;
    }

    // 2) exact rescan of winning 1024-gt chunk (numpy first-max tie semantics)
    const int gb = gci * NN_TILE;
    float bh = -3.0e38f;
    int bg = 0x7FFFFFFF;
#pragma unroll 4
    for (int i = 0; i < NN_TILE / 64; ++i) {
        const int g = gb + i * 64 + lane;             // ascending g per lane
        const float x = gt[g * 6 + 0], y = gt[g * 6 + 1], z = gt[g * 6 + 2];
        const float w = -0.5f * (x * x + y * y + z * z);
        const float h = fmaf(px, x, fmaf(py, y, fmaf(pz, z, w)));
        if (h > bh) { bh = h; bg = g; }
    }
#pragma unroll
    for (int off = 32; off > 0; off >>= 1) {
        const float oh = __shfl_xor(bh, off);
        const int   og = __shfl_xor(bg, off);
        const bool take = (oh > bh) || (oh == bh && og < bg);
        bh = take ? oh : bh;
        bg = take ? og : bg;
    }
    const int j = bg;

    // 3) repulsion max (value only)
    float rm = (lane < RP_NSC) ? repchunk[p * RP_NSC + lane] : -3.0e38f;
#pragma unroll
    for (int off = 32; off > 0; off >>= 1) rm = fmaxf(rm, __shfl_xor(rm, off));

    __shared__ float red[4][3];
    if (lane == 0) {
        const float gx = gt[j * 6 + 0], gy = gt[j * 6 + 1], gz = gt[j * 6 + 2];
        const float dx = px - gx, dy = py - gy, dz = pz - gz;
        const float att = dx * dx + dy * dy + dz * dz;

        const float pnx = pred[p * 6 + 3], pny = pred[p * 6 + 4], pnz = pred[p * 6 + 5];
        const float gnx = gt[j * 6 + 3],   gny = gt[j * 6 + 4],   gnz = gt[j * 6 + 5];
        const float pl = fmaxf(sqrtf(pnx * pnx + pny * pny + pnz * pnz), 1e-5f);
        const float gl = fmaxf(sqrtf(gnx * gnx + gny * gny + gnz * gnz), 1e-5f);
        const float nrm = 1.0f - (pnx * gnx + pny * gny + pnz * gnz) / (pl * gl);

        // min d^2 = |p|^2 - 2 * h_max  (monotone in h)
        float d2 = fmaf(-2.0f, rm, px * px + py * py + pz * pz);
        d2 = fmaxf(d2, 0.0f);
        const float xa = 100.0f * (0.3f - sqrtf(d2));
        const float sp = fmaxf(xa, 0.0f) + log1pf(expf(-fabsf(xa)));

        red[wave][0] = att;
        red[wave][1] = nrm;
        red[wave][2] = sp * sp;
    }
    __syncthreads();
    if (threadIdx.x < 3) {
        partials[blockIdx.x * 3 + threadIdx.x] =
            red[0][threadIdx.x] + red[1][threadIdx.x] +
            red[2][threadIdx.x] + red[3][threadIdx.x];
    }
}

__device__ __forceinline__ float wave_reduce(float v) {
#pragma unroll
    for (int off = 32; off > 0; off >>= 1) v += __shfl_down(v, off, 64);
    return v;
}

__global__ __launch_bounds__(256) void combine_kernel(const float* __restrict__ partials,
                                                      float* __restrict__ out) {
    float a = 0.f, n = 0.f, r = 0.f;
    const int t = threadIdx.x;
#pragma unroll
    for (int k = 0; k < 8; ++k) {
        const int row = t + k * 256;          // 2048 rows
        a += partials[row * 3 + 0];
        n += partials[row * 3 + 1];
        r += partials[row * 3 + 2];
    }
    a = wave_reduce(a);
    n = wave_reduce(n);
    r = wave_reduce(r);

    __shared__ float red[3][4];
    const int wave = t >> 6, lane = t & 63;
    if (lane == 0) { red[0][wave] = a; red[1][wave] = n; red[2][wave] = r; }
    __syncthreads();
    if (t == 0) {
        const float A = red[0][0] + red[0][1] + red[0][2] + red[0][3];
        const float N = red[1][0] + red[1][1] + red[1][2] + red[1][3];
        const float R = red[2][0] + red[2][1] + red[2][2] + red[2][3];
        out[0] = A / (float)(N_PRED * 3) + R / (float)N_PRED + 10.0f * (N / (float)N_PRED);
    }
}

extern "C" void kernel_launch(void* const* d_in, const int* in_sizes, int n_in,
                              void* d_out, int out_size, void* d_ws, size_t ws_size,
                              hipStream_t stream) {
    const float* pred = (const float*)d_in[0];   // (8192, 6)
    const float* gt   = (const float*)d_in[3];   // (32768, 6)
    float* out = (float*)d_out;
    char* ws = (char*)d_ws;

    float* nnchunk  = (float*)ws;                 // [8192][32]
    float* repchunk = (float*)(ws + OFF_REP);     // [8192][16]
    float* partials = (float*)(ws + OFF_PART);    // [2048][3]

    pair_kernel<<<NN_BLOCKS + RP_BLOCKS, BLK, 0, stream>>>(pred, gt, nnchunk, repchunk);
    finalize_kernel<<<N_PRED / 4, 256, 0, stream>>>(pred, gt, nnchunk, repchunk, partials);
    combine_kernel<<<1, 256, 0, stream>>>(partials, out);
}